// Round 1
// baseline (2005.014 us; speedup 1.0000x reference)
//
#include <hip/hip_runtime.h>
#include <math.h>

// Problem constants (B=2, S=4096, D=512, H=8, dh=64)
#define BATCH  2
#define SLEN   4096
#define DMODEL 512
#define NH     8
#define DH     64
#define NROWS  (BATCH * SLEN)   // 8192

// ---------------------------------------------------------------------------
// GEMM: C[M,N] = A[M,K] @ W[K,N] + bias[N]
// Tile 64x64, 256 threads, 4x4 per-thread microtile, BK=16.
// HEADSPLIT=1: store C[n_row, d] to [B,H,S,dh] layout (for Q/K/V projections).
// ---------------------------------------------------------------------------
template<int HEADSPLIT>
__global__ __launch_bounds__(256)
void gemm_bias(const float* __restrict__ A, const float* __restrict__ W,
               const float* __restrict__ bias, float* __restrict__ C,
               int M, int N, int K)
{
    __shared__ float As[16][68];   // [k][m], pad 4 keeps float4 16B-aligned, <=2-way conflicts
    __shared__ float Bs[16][64];   // [k][n]

    const int tid = threadIdx.x;
    const int m0 = blockIdx.y * 64;
    const int n0 = blockIdx.x * 64;
    const int ty = tid >> 4;        // 0..15 -> row group
    const int tx = tid & 15;        // 0..15 -> col group

    // staging roles
    const int la_m = tid >> 2;          // 0..63
    const int la_k = (tid & 3) << 2;    // 0,4,8,12
    const int lb_k = tid >> 4;          // 0..15
    const int lb_n = (tid & 15) << 2;   // 0..60

    float acc[4][4] = {};

    for (int k0 = 0; k0 < K; k0 += 16) {
        float4 av = *(const float4*)&A[(size_t)(m0 + la_m) * K + k0 + la_k];
        float4 bv = *(const float4*)&W[(size_t)(k0 + lb_k) * N + n0 + lb_n];
        __syncthreads();   // previous iteration's readers done
        As[la_k + 0][la_m] = av.x;
        As[la_k + 1][la_m] = av.y;
        As[la_k + 2][la_m] = av.z;
        As[la_k + 3][la_m] = av.w;
        *(float4*)&Bs[lb_k][lb_n] = bv;
        __syncthreads();
        #pragma unroll
        for (int k = 0; k < 16; ++k) {
            float4 a = *(const float4*)&As[k][ty << 2];
            float4 b = *(const float4*)&Bs[k][tx << 2];
            acc[0][0] += a.x * b.x; acc[0][1] += a.x * b.y; acc[0][2] += a.x * b.z; acc[0][3] += a.x * b.w;
            acc[1][0] += a.y * b.x; acc[1][1] += a.y * b.y; acc[1][2] += a.y * b.z; acc[1][3] += a.y * b.w;
            acc[2][0] += a.z * b.x; acc[2][1] += a.z * b.y; acc[2][2] += a.z * b.z; acc[2][3] += a.z * b.w;
            acc[3][0] += a.w * b.x; acc[3][1] += a.w * b.y; acc[3][2] += a.w * b.z; acc[3][3] += a.w * b.w;
        }
    }

    float4 bb = *(const float4*)&bias[n0 + (tx << 2)];
    #pragma unroll
    for (int i = 0; i < 4; ++i) {
        const int m = m0 + (ty << 2) + i;
        float4 o;
        o.x = acc[i][0] + bb.x;
        o.y = acc[i][1] + bb.y;
        o.z = acc[i][2] + bb.z;
        o.w = acc[i][3] + bb.w;
        if (HEADSPLIT) {
            // n = n0 + tx*4 .. +3 all inside one head (n0 % 64 == 0)
            const int h  = n0 >> 6;
            const int hd = tx << 2;
            const int b  = m >> 12;          // /SLEN
            const int s  = m & (SLEN - 1);
            float* dst = C + (((size_t)b * NH + h) * SLEN + s) * DH + hd;
            *(float4*)dst = o;
        } else {
            *(float4*)&C[(size_t)m * N + n0 + (tx << 2)] = o;
        }
    }
}

// ---------------------------------------------------------------------------
// Flash attention fp32. Q,K,V in [B,H,S,64] layout. One block = 16 query rows
// of one (b,h); loops over 64-key tiles with online softmax.
// Thread (r = tid/16, c = tid%16): scores for keys j = c+16*jj, output dims 4c..4c+3.
// Mask semantics match reference exactly: scaled score replaced by -1e9.
// ---------------------------------------------------------------------------
__global__ __launch_bounds__(256)
void flash_attn(const float* __restrict__ Q, const float* __restrict__ K,
                const float* __restrict__ V, const int* __restrict__ mask,
                float* __restrict__ X)
{
    __shared__ float Qs[16][68];
    __shared__ float Ks[64][68];
    __shared__ float Vs[64][68];
    __shared__ float Ps[16][72];
    __shared__ int   Ms[64];

    const int tid = threadIdx.x;
    const int bh  = blockIdx.y;          // 0..15
    const int b   = bh >> 3;
    const int h   = bh & 7;
    const int q0  = blockIdx.x << 4;
    const int r   = tid >> 4;            // 0..15 query row
    const int c   = tid & 15;            // 0..15 lane in row

    const float* Qb = Q + ((size_t)bh * SLEN + q0) * DH;
    const float* Kb = K + (size_t)bh * SLEN * DH;
    const float* Vb = V + (size_t)bh * SLEN * DH;
    const int*  mrow = mask + (size_t)b * SLEN;

    // load Q tile (1024 floats, one float4/thread)
    {
        const int e = tid << 2;
        const int row = e >> 6, col = e & 63;
        *(float4*)&Qs[row][col] = *(const float4*)&Qb[row * DH + col];
    }

    float m_run = -INFINITY;
    float l_run = 0.f;
    float4 acc = {0.f, 0.f, 0.f, 0.f};

    for (int kt = 0; kt < SLEN / 64; ++kt) {
        const int k0 = kt << 6;
        __syncthreads();   // previous tile's PV reads done (also publishes Qs on iter 0)
        #pragma unroll
        for (int i = 0; i < 4; ++i) {
            const int e = (i << 10) + (tid << 2);
            const int row = e >> 6, col = e & 63;
            *(float4*)&Ks[row][col] = *(const float4*)&Kb[(size_t)(k0 + row) * DH + col];
        }
        #pragma unroll
        for (int i = 0; i < 4; ++i) {
            const int e = (i << 10) + (tid << 2);
            const int row = e >> 6, col = e & 63;
            *(float4*)&Vs[row][col] = *(const float4*)&Vb[(size_t)(k0 + row) * DH + col];
        }
        if (tid < 64) Ms[tid] = mrow[k0 + tid];
        __syncthreads();

        // ---- scores: s[jj] = q_row . k_{c+16jj}
        float s0 = 0.f, s1 = 0.f, s2 = 0.f, s3 = 0.f;
        #pragma unroll
        for (int k4 = 0; k4 < 16; ++k4) {
            float4 qv = *(const float4*)&Qs[r][k4 << 2];
            float4 kv0 = *(const float4*)&Ks[c][k4 << 2];
            float4 kv1 = *(const float4*)&Ks[c + 16][k4 << 2];
            float4 kv2 = *(const float4*)&Ks[c + 32][k4 << 2];
            float4 kv3 = *(const float4*)&Ks[c + 48][k4 << 2];
            s0 += qv.x * kv0.x + qv.y * kv0.y + qv.z * kv0.z + qv.w * kv0.w;
            s1 += qv.x * kv1.x + qv.y * kv1.y + qv.z * kv1.z + qv.w * kv1.w;
            s2 += qv.x * kv2.x + qv.y * kv2.y + qv.z * kv2.z + qv.w * kv2.w;
            s3 += qv.x * kv3.x + qv.y * kv3.y + qv.z * kv3.z + qv.w * kv3.w;
        }
        s0 *= 0.125f; s1 *= 0.125f; s2 *= 0.125f; s3 *= 0.125f;
        if (Ms[c]      == 0) s0 = -1e9f;
        if (Ms[c + 16] == 0) s1 = -1e9f;
        if (Ms[c + 32] == 0) s2 = -1e9f;
        if (Ms[c + 48] == 0) s3 = -1e9f;

        // ---- online softmax update
        float mx = fmaxf(fmaxf(s0, s1), fmaxf(s2, s3));
        #pragma unroll
        for (int off = 1; off < 16; off <<= 1)
            mx = fmaxf(mx, __shfl_xor(mx, off));
        const float m_new = fmaxf(m_run, mx);
        const float corr  = __expf(m_run - m_new);   // m_run=-inf -> 0
        const float p0 = __expf(s0 - m_new);
        const float p1 = __expf(s1 - m_new);
        const float p2 = __expf(s2 - m_new);
        const float p3 = __expf(s3 - m_new);
        float psum = p0 + p1 + p2 + p3;
        #pragma unroll
        for (int off = 1; off < 16; off <<= 1)
            psum += __shfl_xor(psum, off);
        l_run = l_run * corr + psum;
        m_run = m_new;
        acc.x *= corr; acc.y *= corr; acc.z *= corr; acc.w *= corr;

        Ps[r][c]      = p0;
        Ps[r][c + 16] = p1;
        Ps[r][c + 32] = p2;
        Ps[r][c + 48] = p3;
        __syncthreads();

        // ---- PV: acc[d] += sum_j p_j * V[j][d], d = 4c..4c+3
        #pragma unroll 8
        for (int j = 0; j < 64; ++j) {
            const float pj = Ps[r][j];
            float4 vv = *(const float4*)&Vs[j][c << 2];
            acc.x += pj * vv.x;
            acc.y += pj * vv.y;
            acc.z += pj * vv.z;
            acc.w += pj * vv.w;
        }
    }

    const float inv = 1.0f / l_run;
    acc.x *= inv; acc.y *= inv; acc.z *= inv; acc.w *= inv;
    // store to X[B,S,D] with d = h*64 + 4c
    float* dst = X + ((size_t)(b * SLEN + q0 + r)) * DMODEL + h * DH + (c << 2);
    *(float4*)dst = acc;
}

// ---------------------------------------------------------------------------
extern "C" void kernel_launch(void* const* d_in, const int* in_sizes, int n_in,
                              void* d_out, int out_size, void* d_ws, size_t ws_size,
                              hipStream_t stream)
{
    const float* query  = (const float*)d_in[0];
    const float* key_in = (const float*)d_in[1];
    const float* value  = (const float*)d_in[2];
    const int*   mask   = (const int*)  d_in[3];
    const float* Wq = (const float*)d_in[4];
    const float* bq = (const float*)d_in[5];
    const float* Wk = (const float*)d_in[6];
    const float* bk = (const float*)d_in[7];
    const float* Wv = (const float*)d_in[8];
    const float* bv = (const float*)d_in[9];
    const float* Wo = (const float*)d_in[10];
    const float* bo = (const float*)d_in[11];
    float* out = (float*)d_out;

    const size_t NELEM = (size_t)BATCH * SLEN * DMODEL;  // 4,194,304
    float* qws = (float*)d_ws;
    float* kws = qws + NELEM;
    float* vws = kws + NELEM;
    float* xws = vws + NELEM;
    (void)in_sizes; (void)n_in; (void)out_size; (void)ws_size;

    dim3 gg(DMODEL / 64, NROWS / 64);   // (8, 128)
    gemm_bias<1><<<gg, 256, 0, stream>>>(query,  Wq, bq, qws, NROWS, DMODEL, DMODEL);
    gemm_bias<1><<<gg, 256, 0, stream>>>(key_in, Wk, bk, kws, NROWS, DMODEL, DMODEL);
    gemm_bias<1><<<gg, 256, 0, stream>>>(value,  Wv, bv, vws, NROWS, DMODEL, DMODEL);

    flash_attn<<<dim3(SLEN / 16, BATCH * NH), 256, 0, stream>>>(qws, kws, vws, mask, xws);

    gemm_bias<0><<<gg, 256, 0, stream>>>(xws, Wo, bo, out, NROWS, DMODEL, DMODEL);
}

// Round 2
// 514.323 us; speedup vs baseline: 3.8984x; 3.8984x over previous
//
#include <hip/hip_runtime.h>
#include <math.h>

// Problem constants (B=2, S=4096, D=512, H=8, dh=64)
#define BATCH  2
#define SLEN   4096
#define DMODEL 512
#define NH     8
#define DH     64
#define NROWS  (BATCH * SLEN)   // 8192

typedef __attribute__((ext_vector_type(8))) short bf16x8;
typedef __attribute__((ext_vector_type(4))) float f32x4;

__device__ __forceinline__ unsigned short f2bf(float f) {
    unsigned u = __builtin_bit_cast(unsigned, f);
    u = (u + 0x7fffu + ((u >> 16) & 1u)) >> 16;   // RNE
    return (unsigned short)u;
}

__device__ __forceinline__ void gload16(const void* g, void* l) {
    __builtin_amdgcn_global_load_lds(
        (const __attribute__((address_space(1))) unsigned int*)g,
        (__attribute__((address_space(3))) unsigned int*)l, 16, 0, 0);
}

// ---------------------------------------------------------------------------
// GEMM: C[M,N] = A[M,K] @ W[K,N] + bias[N]. Tile 64x64, 256 thr, 4x4 microtile.
// OUTMODE 0: fp32 [M,N] (output projection)
// OUTMODE 1: bf16 head-split [B,H,S,dh]   (Q, K)
// OUTMODE 2: bf16 transposed [B,H,dh,S]   (V^T, so flash PV reads are row-major)
// ---------------------------------------------------------------------------
template<int OUTMODE>
__global__ __launch_bounds__(256)
void gemm_bias(const float* __restrict__ A, const float* __restrict__ W,
               const float* __restrict__ bias, void* __restrict__ Cout,
               int M, int N, int K)
{
    __shared__ float As[16][68];
    __shared__ float Bs[16][64];

    const int tid = threadIdx.x;
    const int m0 = blockIdx.y * 64;
    const int n0 = blockIdx.x * 64;
    const int ty = tid >> 4;
    const int tx = tid & 15;

    const int la_m = tid >> 2;
    const int la_k = (tid & 3) << 2;
    const int lb_k = tid >> 4;
    const int lb_n = (tid & 15) << 2;

    float acc[4][4] = {};

    for (int k0 = 0; k0 < K; k0 += 16) {
        float4 av = *(const float4*)&A[(size_t)(m0 + la_m) * K + k0 + la_k];
        float4 bv = *(const float4*)&W[(size_t)(k0 + lb_k) * N + n0 + lb_n];
        __syncthreads();
        As[la_k + 0][la_m] = av.x;
        As[la_k + 1][la_m] = av.y;
        As[la_k + 2][la_m] = av.z;
        As[la_k + 3][la_m] = av.w;
        *(float4*)&Bs[lb_k][lb_n] = bv;
        __syncthreads();
        #pragma unroll
        for (int k = 0; k < 16; ++k) {
            float4 a = *(const float4*)&As[k][ty << 2];
            float4 b = *(const float4*)&Bs[k][tx << 2];
            acc[0][0] += a.x * b.x; acc[0][1] += a.x * b.y; acc[0][2] += a.x * b.z; acc[0][3] += a.x * b.w;
            acc[1][0] += a.y * b.x; acc[1][1] += a.y * b.y; acc[1][2] += a.y * b.z; acc[1][3] += a.y * b.w;
            acc[2][0] += a.z * b.x; acc[2][1] += a.z * b.y; acc[2][2] += a.z * b.z; acc[2][3] += a.z * b.w;
            acc[3][0] += a.w * b.x; acc[3][1] += a.w * b.y; acc[3][2] += a.w * b.z; acc[3][3] += a.w * b.w;
        }
    }

    float4 bb = *(const float4*)&bias[n0 + (tx << 2)];
    const int h  = n0 >> 6;

    if (OUTMODE == 0) {
        float* C = (float*)Cout;
        #pragma unroll
        for (int i = 0; i < 4; ++i) {
            const int m = m0 + (ty << 2) + i;
            float4 o = { acc[i][0] + bb.x, acc[i][1] + bb.y, acc[i][2] + bb.z, acc[i][3] + bb.w };
            *(float4*)&C[(size_t)m * N + n0 + (tx << 2)] = o;
        }
    } else if (OUTMODE == 1) {
        unsigned short* C = (unsigned short*)Cout;
        const int hd = tx << 2;
        #pragma unroll
        for (int i = 0; i < 4; ++i) {
            const int m = m0 + (ty << 2) + i;
            const int b = m >> 12;
            const int s = m & (SLEN - 1);
            ushort4 o;
            o.x = f2bf(acc[i][0] + bb.x);
            o.y = f2bf(acc[i][1] + bb.y);
            o.z = f2bf(acc[i][2] + bb.z);
            o.w = f2bf(acc[i][3] + bb.w);
            *(ushort4*)(C + (((size_t)b * NH + h) * SLEN + s) * DH + hd) = o;
        }
    } else {
        // V^T: [B,H,dh,S]; pack 4 consecutive s per store
        unsigned short* C = (unsigned short*)Cout;
        const int b  = m0 >> 12;
        const int s0 = (m0 & (SLEN - 1)) + (ty << 2);
        const float bj[4] = { bb.x, bb.y, bb.z, bb.w };
        #pragma unroll
        for (int j = 0; j < 4; ++j) {
            const int hd = (tx << 2) + j;
            ushort4 o;
            o.x = f2bf(acc[0][j] + bj[j]);
            o.y = f2bf(acc[1][j] + bj[j]);
            o.z = f2bf(acc[2][j] + bj[j]);
            o.w = f2bf(acc[3][j] + bj[j]);
            *(ushort4*)(C + (((size_t)b * NH + h) * DH + hd) * SLEN + s0) = o;
        }
    }
}

// ---------------------------------------------------------------------------
// Flash attention, bf16 MFMA (16x16x32), fp32 accumulate + fp32 softmax state.
// Block = 256 thr = 4 waves; wave w owns q-rows [q0+16w, q0+16w+16); KVBLK=64.
// K LDS tile [64 keys][64 d] and V^T LDS tile [64 d][64 keys], both bf16 with
// 16B-chunk XOR swizzle (chunk ^= row&7) applied on the GLOBAL SOURCE address
// (global_load_lds dest is linear) and on the ds_read address (same involution).
// MFMA fragment conventions (verified m89 layouts):
//   A: lane holds A[row=l&15][k=(l>>4)*8+j]; B: B[k=(l>>4)*8+j][col=l&15]
//   C/D: lane holds D[row=(l>>4)*4+reg][col=l&15]
// ---------------------------------------------------------------------------
__global__ __launch_bounds__(256)
void flash_mfma(const unsigned short* __restrict__ Qg,
                const unsigned short* __restrict__ Kg,
                const unsigned short* __restrict__ Vtg,
                const int* __restrict__ mask,
                float* __restrict__ X)
{
    __shared__ char KsB[8192];                 // [64 keys][128B], swizzled chunks
    __shared__ char VsB[8192];                 // [64 d][128B], swizzled chunks
    __shared__ unsigned short Ps[4][16][72];   // per-wave P tile, pad to 144B rows
    __shared__ int Ms[64];

    const int tid  = threadIdx.x;
    const int lane = tid & 63;
    const int w    = tid >> 6;
    const int g    = lane >> 4;       // 0..3
    const int c    = lane & 15;
    const int cx   = c & 7;
    const int bh   = blockIdx.y;
    const int b    = bh >> 3;
    const int h    = bh & 7;
    const int q0   = blockIdx.x << 6;

    const unsigned short* Qb  = Qg  + ((size_t)bh * SLEN + q0 + w * 16) * DH;
    const unsigned short* Kb  = Kg  + (size_t)bh * SLEN * DH;
    const unsigned short* Vtb = Vtg + (size_t)bh * DH * SLEN;
    const int* mrow = mask + b * SLEN;

    // Q fragments (held in registers for the whole kernel)
    bf16x8 qf0 = *(const bf16x8*)(const void*)(Qb + (size_t)c * DH + g * 8);
    bf16x8 qf1 = *(const bf16x8*)(const void*)(Qb + (size_t)c * DH + 32 + g * 8);

    // staging geometry: lane -> (row r = seg*32 + w*8 + lane/8, phys chunk lane%8)
    const int lane8 = lane >> 3;
    const int schk  = (lane & 7) ^ lane8;     // source chunk (r&7 == lane8 here)
    const int r0    = w * 8 + lane8;
    const unsigned short* kSrc0 = Kb  + (size_t)r0 * DH + schk * 8;
    const unsigned short* kSrc1 = Kb  + (size_t)(r0 + 32) * DH + schk * 8;
    const unsigned short* vSrc0 = Vtb + (size_t)r0 * SLEN + schk * 8;
    const unsigned short* vSrc1 = Vtb + (size_t)(r0 + 32) * SLEN + schk * 8;
    char* kDst0 = KsB + w * 1024;
    char* kDst1 = KsB + 4096 + w * 1024;
    char* vDst0 = VsB + w * 1024;
    char* vDst1 = VsB + 4096 + w * 1024;

    float mrun[4] = { -INFINITY, -INFINITY, -INFINITY, -INFINITY };
    float lrun[4] = { 0.f, 0.f, 0.f, 0.f };
    f32x4 oacc[4];
    #pragma unroll
    for (int dt = 0; dt < 4; ++dt) oacc[dt] = (f32x4){0.f, 0.f, 0.f, 0.f};

    for (int kt = 0; kt < SLEN / 64; ++kt) {
        const int k0 = kt << 6;
        __syncthreads();                       // all waves done reading prev tile
        gload16(kSrc0 + (size_t)k0 * DH, kDst0);
        gload16(kSrc1 + (size_t)k0 * DH, kDst1);
        gload16(vSrc0 + k0, vDst0);
        gload16(vSrc1 + k0, vDst1);
        if (tid < 64) Ms[tid] = mrow[k0 + tid];
        __syncthreads();                       // drains vmcnt+lgkmcnt

        // ---- S = Q K^T (per wave: 16q x 64k as 4 kk-tiles)
        f32x4 sacc[4];
        #pragma unroll
        for (int kk = 0; kk < 4; ++kk) sacc[kk] = (f32x4){0.f, 0.f, 0.f, 0.f};
        #pragma unroll
        for (int ks = 0; ks < 2; ++ks) {
            bf16x8 qf = ks ? qf1 : qf0;
            #pragma unroll
            for (int kk = 0; kk < 4; ++kk) {
                const int rrow = kk * 16 + c;
                const int off  = rrow * 128 + (((ks * 4 + g) ^ cx) << 4);
                bf16x8 kf = *(const bf16x8*)(const void*)(KsB + off);
                sacc[kk] = __builtin_amdgcn_mfma_f32_16x16x32_bf16(qf, kf, sacc[kk], 0, 0, 0);
            }
        }

        // ---- scale + mask (exact reference semantics: masked -> -1e9)
        int mk[4];
        #pragma unroll
        for (int kk = 0; kk < 4; ++kk) mk[kk] = Ms[kk * 16 + c];
        #pragma unroll
        for (int kk = 0; kk < 4; ++kk) {
            #pragma unroll
            for (int r = 0; r < 4; ++r) {
                const float sv = sacc[kk][r] * 0.125f;
                sacc[kk][r] = (mk[kk] == 0) ? -1e9f : sv;
            }
        }

        // ---- online softmax (per q-row r; keys split 4/kk in-lane x 16 lanes)
        float mx[4], corr[4], psum[4];
        #pragma unroll
        for (int r = 0; r < 4; ++r)
            mx[r] = fmaxf(fmaxf(sacc[0][r], sacc[1][r]), fmaxf(sacc[2][r], sacc[3][r]));
        #pragma unroll
        for (int off = 1; off < 16; off <<= 1) {
            #pragma unroll
            for (int r = 0; r < 4; ++r) mx[r] = fmaxf(mx[r], __shfl_xor(mx[r], off));
        }
        #pragma unroll
        for (int r = 0; r < 4; ++r) {
            const float mn = fmaxf(mrun[r], mx[r]);
            corr[r] = __expf(mrun[r] - mn);
            mrun[r] = mn;
            float ps = 0.f;
            #pragma unroll
            for (int kk = 0; kk < 4; ++kk) {
                const float p = __expf(sacc[kk][r] - mn);
                sacc[kk][r] = p;
                ps += p;
            }
            psum[r] = ps;
        }
        #pragma unroll
        for (int off = 1; off < 16; off <<= 1) {
            #pragma unroll
            for (int r = 0; r < 4; ++r) psum[r] += __shfl_xor(psum[r], off);
        }
        #pragma unroll
        for (int r = 0; r < 4; ++r) lrun[r] = lrun[r] * corr[r] + psum[r];
        #pragma unroll
        for (int dt = 0; dt < 4; ++dt) {
            #pragma unroll
            for (int r = 0; r < 4; ++r) oacc[dt][r] *= corr[r];
        }

        // ---- P -> LDS (bf16), per-wave region, wave-internal ordering only
        #pragma unroll
        for (int kk = 0; kk < 4; ++kk) {
            #pragma unroll
            for (int r = 0; r < 4; ++r)
                Ps[w][g * 4 + r][kk * 16 + c] = f2bf(sacc[kk][r]);
        }

        // ---- O += P V  (A = P frag from own Ps region, B = V^T rows)
        #pragma unroll
        for (int ks = 0; ks < 2; ++ks) {
            bf16x8 pf = *(const bf16x8*)(const void*)&Ps[w][c][ks * 32 + g * 8];
            #pragma unroll
            for (int dt = 0; dt < 4; ++dt) {
                const int rr  = dt * 16 + c;
                const int off = rr * 128 + (((ks * 4 + g) ^ cx) << 4);
                bf16x8 vf = *(const bf16x8*)(const void*)(VsB + off);
                oacc[dt] = __builtin_amdgcn_mfma_f32_16x16x32_bf16(pf, vf, oacc[dt], 0, 0, 0);
            }
        }
    }

    // ---- epilogue: normalize and store fp32 X[B,S,D]
    const int qg0 = q0 + w * 16;
    #pragma unroll
    for (int r = 0; r < 4; ++r) {
        const float inv = 1.0f / lrun[r];
        const int qrow = qg0 + g * 4 + r;
        float* dst = X + ((size_t)b * SLEN + qrow) * DMODEL + h * DH;
        #pragma unroll
        for (int dt = 0; dt < 4; ++dt) dst[dt * 16 + c] = oacc[dt][r] * inv;
    }
}

// ---------------------------------------------------------------------------
extern "C" void kernel_launch(void* const* d_in, const int* in_sizes, int n_in,
                              void* d_out, int out_size, void* d_ws, size_t ws_size,
                              hipStream_t stream)
{
    const float* query  = (const float*)d_in[0];
    const float* key_in = (const float*)d_in[1];
    const float* value  = (const float*)d_in[2];
    const int*   mask   = (const int*)  d_in[3];
    const float* Wq = (const float*)d_in[4];
    const float* bq = (const float*)d_in[5];
    const float* Wk = (const float*)d_in[6];
    const float* bk = (const float*)d_in[7];
    const float* Wv = (const float*)d_in[8];
    const float* bv = (const float*)d_in[9];
    const float* Wo = (const float*)d_in[10];
    const float* bo = (const float*)d_in[11];
    float* out = (float*)d_out;
    (void)in_sizes; (void)n_in; (void)out_size; (void)ws_size;

    const size_t NELEM = (size_t)BATCH * SLEN * DMODEL;  // 4,194,304
    unsigned short* qbf  = (unsigned short*)d_ws;
    unsigned short* kbf  = qbf + NELEM;
    unsigned short* vtbf = kbf + NELEM;
    float*          xws  = (float*)(vtbf + NELEM);

    dim3 gg(DMODEL / 64, NROWS / 64);   // (8, 128)
    gemm_bias<1><<<gg, 256, 0, stream>>>(query,  Wq, bq, qbf,  NROWS, DMODEL, DMODEL);
    gemm_bias<1><<<gg, 256, 0, stream>>>(key_in, Wk, bk, kbf,  NROWS, DMODEL, DMODEL);
    gemm_bias<2><<<gg, 256, 0, stream>>>(value,  Wv, bv, vtbf, NROWS, DMODEL, DMODEL);

    flash_mfma<<<dim3(SLEN / 64, BATCH * NH), 256, 0, stream>>>(qbf, kbf, vtbf, mask, xws);

    gemm_bias<0><<<gg, 256, 0, stream>>>(xws, Wo, bo, out, NROWS, DMODEL, DMODEL);
}

// Round 3
// 260.914 us; speedup vs baseline: 7.6846x; 1.9712x over previous
//
#include <hip/hip_runtime.h>
#include <math.h>

// Problem constants (B=2, S=4096, D=512, H=8, dh=64)
#define BATCH  2
#define SLEN   4096
#define DMODEL 512
#define NH     8
#define DH     64
#define NROWS  (BATCH * SLEN)   // 8192

// Q-side fold: scores*(1/8)*log2(e) so softmax uses raw v_exp_f32 (2^x)
#define QSCALE 0.18033688011112042f

typedef __attribute__((ext_vector_type(8))) _Float16 f16x8;
typedef __attribute__((ext_vector_type(4))) _Float16 f16x4;
typedef __attribute__((ext_vector_type(4))) float    f32x4;

__device__ __forceinline__ float exp2_hw(float x) {
    float r; asm("v_exp_f32 %0, %1" : "=v"(r) : "v"(x)); return r;   // D = 2^S0
}

__device__ __forceinline__ void gload16(const void* g, void* l) {
    __builtin_amdgcn_global_load_lds(
        (const __attribute__((address_space(1))) unsigned int*)g,
        (__attribute__((address_space(3))) unsigned int*)l, 16, 0, 0);
}

// ---------------------------------------------------------------------------
// Weights: fp32 [K][N] -> fp16 transposed [N][K] (B-fragment reads become rows).
// z selects which weight; Wq additionally scaled by QSCALE.
// ---------------------------------------------------------------------------
__global__ __launch_bounds__(256)
void cast_weights(const float* __restrict__ W0, const float* __restrict__ W1,
                  const float* __restrict__ W2, const float* __restrict__ W3,
                  _Float16* __restrict__ T0, _Float16* __restrict__ T1,
                  _Float16* __restrict__ T2, _Float16* __restrict__ T3)
{
    const int z = blockIdx.z;
    const float* W = (z == 0) ? W0 : (z == 1) ? W1 : (z == 2) ? W2 : W3;
    _Float16*    T = (z == 0) ? T0 : (z == 1) ? T1 : (z == 2) ? T2 : T3;
    const float sc = (z == 0) ? QSCALE : 1.0f;

    __shared__ float Ls[32][33];
    const int n0 = blockIdx.x * 32, k0 = blockIdx.y * 32;
    const int row = threadIdx.x >> 3;
    const int c4  = (threadIdx.x & 7) << 2;

    float4 v = *(const float4*)&W[(size_t)(k0 + row) * DMODEL + n0 + c4];
    Ls[row][c4 + 0] = v.x; Ls[row][c4 + 1] = v.y;
    Ls[row][c4 + 2] = v.z; Ls[row][c4 + 3] = v.w;
    __syncthreads();

    f16x4 o;
    #pragma unroll
    for (int j = 0; j < 4; ++j) o[j] = (_Float16)(Ls[c4 + j][row] * sc);
    *(f16x4*)&T[(size_t)(n0 + row) * DMODEL + k0 + c4] = o;
}

// ---------------------------------------------------------------------------
// fp16 MFMA GEMM: C[8192,512] = A[8192,512] @ WT^T + bias. BM=BN=BK=64, 4 waves.
// AMODE 0: A fp16 in global (gload16 direct)   1: A fp32 (reg-stage + cvt)
// OUTMODE 0: fp32 [M,N] + bias                 (output projection)
//         1: fp16 head-split [B,H,S,64] + bias*bscale   (Q, K)
//         2: fp16 transposed [B,H,64,S] + bias          (V^T via LDS transpose)
// LDS tiles [64 rows][128B] with 16B-chunk XOR swizzle (chunk ^= row&7).
// ---------------------------------------------------------------------------
template<int AMODE, int OUTMODE>
__global__ __launch_bounds__(256)
void gemm_mfma(const void* __restrict__ Ag, const _Float16* __restrict__ WTg,
               const float* __restrict__ bias, float bscale, void* __restrict__ Cout)
{
    extern __shared__ char smem[];
    char* Asb = smem;            // 8 KB
    char* Bsb = smem + 8192;     // 8 KB
    _Float16* Tr = (_Float16*)(smem + 16384);   // 12 KB, OUTMODE==2 only

    const int tid  = threadIdx.x;
    const int lane = tid & 63;
    const int w    = tid >> 6;
    const int g    = lane >> 4;
    const int c    = lane & 15;
    const int m0   = blockIdx.y * 64;
    const int n0   = blockIdx.x * 64;

    // gload staging geometry (rows 8w+lane/8 (+32), source chunk pre-swizzled)
    const int lrow = lane >> 3;
    const int schk = (lane & 7) ^ lrow;
    const int brow = w * 8 + lrow;
    const _Float16* bSrc0 = WTg + (size_t)(n0 + brow) * DMODEL + schk * 8;
    const _Float16* bSrc1 = WTg + (size_t)(n0 + brow + 32) * DMODEL + schk * 8;
    char* bDst = Bsb + w * 1024;
    char* aDst = Asb + w * 1024;

    const _Float16* aSrc0 = nullptr; const _Float16* aSrc1 = nullptr;
    const float* aF = nullptr;
    const int arow = tid >> 2;            // 0..63 (AMODE 1)
    const int acp  = (tid & 3) << 1;      // chunk pair
    if constexpr (AMODE == 0) {
        const _Float16* Ah = (const _Float16*)Ag;
        aSrc0 = Ah + (size_t)(m0 + brow) * DMODEL + schk * 8;
        aSrc1 = Ah + (size_t)(m0 + brow + 32) * DMODEL + schk * 8;
    } else {
        aF = (const float*)Ag + (size_t)(m0 + arow) * DMODEL;
    }

    f32x4 acc[4];
    #pragma unroll
    for (int nt = 0; nt < 4; ++nt) acc[nt] = (f32x4){0.f, 0.f, 0.f, 0.f};

    for (int k0 = 0; k0 < DMODEL; k0 += 64) {
        float4 a0, a1, a2, a3;
        if constexpr (AMODE == 1) {
            const float* p = aF + k0 + acp * 8;
            a0 = *(const float4*)(p + 0);  a1 = *(const float4*)(p + 4);
            a2 = *(const float4*)(p + 8);  a3 = *(const float4*)(p + 12);
        }
        __syncthreads();   // prev tile's readers done
        if constexpr (AMODE == 0) {
            gload16(aSrc0 + k0, aDst);
            gload16(aSrc1 + k0, aDst + 4096);
        } else {
            f16x8 h0, h1;
            h0[0]=(_Float16)a0.x; h0[1]=(_Float16)a0.y; h0[2]=(_Float16)a0.z; h0[3]=(_Float16)a0.w;
            h0[4]=(_Float16)a1.x; h0[5]=(_Float16)a1.y; h0[6]=(_Float16)a1.z; h0[7]=(_Float16)a1.w;
            h1[0]=(_Float16)a2.x; h1[1]=(_Float16)a2.y; h1[2]=(_Float16)a2.z; h1[3]=(_Float16)a2.w;
            h1[4]=(_Float16)a3.x; h1[5]=(_Float16)a3.y; h1[6]=(_Float16)a3.z; h1[7]=(_Float16)a3.w;
            *(f16x8*)(Asb + arow * 128 + (((acp    ) ^ (arow & 7)) << 4)) = h0;
            *(f16x8*)(Asb + arow * 128 + (((acp + 1) ^ (arow & 7)) << 4)) = h1;
        }
        gload16(bSrc0 + k0, bDst);
        gload16(bSrc1 + k0, bDst + 4096);
        __syncthreads();   // drains vmcnt + lgkmcnt

        #pragma unroll
        for (int ks = 0; ks < 2; ++ks) {
            const int ar = w * 16 + c;
            f16x8 af = *(const f16x8*)(Asb + ar * 128 + ((((ks << 2) + g) ^ (ar & 7)) << 4));
            #pragma unroll
            for (int nt = 0; nt < 4; ++nt) {
                const int br = nt * 16 + c;
                f16x8 bf = *(const f16x8*)(Bsb + br * 128 + ((((ks << 2) + g) ^ (br & 7)) << 4));
                acc[nt] = __builtin_amdgcn_mfma_f32_16x16x32_f16(af, bf, acc[nt], 0, 0, 0);
            }
        }
    }

    // ---- epilogue (C/D layout: lane (g,c) holds D[row=g*4+r][col=nt*16+c])
    const int h = n0 >> 6;
    if constexpr (OUTMODE == 0) {
        float* C = (float*)Cout;
        #pragma unroll
        for (int nt = 0; nt < 4; ++nt) {
            const float bb = bias[n0 + nt * 16 + c];
            #pragma unroll
            for (int r = 0; r < 4; ++r) {
                const int m = m0 + w * 16 + g * 4 + r;
                C[(size_t)m * DMODEL + n0 + nt * 16 + c] = acc[nt][r] + bb;
            }
        }
    } else if constexpr (OUTMODE == 1) {
        _Float16* C = (_Float16*)Cout;
        #pragma unroll
        for (int nt = 0; nt < 4; ++nt) {
            const float bb = bias[n0 + nt * 16 + c] * bscale;
            const int hd = nt * 16 + c;
            #pragma unroll
            for (int r = 0; r < 4; ++r) {
                const int m = m0 + w * 16 + g * 4 + r;
                const int b = m >> 12;
                const int s = m & (SLEN - 1);
                C[(((size_t)b * NH + h) * SLEN + s) * DH + hd] = (_Float16)(acc[nt][r] + bb);
            }
        }
    } else {
        // V^T: per-wave LDS transpose [64 n][24 pad] then 32B row stores
        #pragma unroll
        for (int nt = 0; nt < 4; ++nt) {
            const float bb = bias[n0 + nt * 16 + c];
            #pragma unroll
            for (int r = 0; r < 4; ++r)
                Tr[(size_t)(w * 64 + nt * 16 + c) * 24 + g * 4 + r] = (_Float16)(acc[nt][r] + bb);
        }
        // same-wave ds_write -> ds_read; compiler inserts lgkmcnt
        const int n = lane;
        f16x8 t0 = *(const f16x8*)&Tr[(size_t)(w * 64 + n) * 24 + 0];
        f16x8 t1 = *(const f16x8*)&Tr[(size_t)(w * 64 + n) * 24 + 8];
        const int b = m0 >> 12;
        const int s = (m0 & (SLEN - 1)) + w * 16;
        _Float16* dst = (_Float16*)Cout + (((size_t)b * NH + h) * DH + n) * SLEN + s;
        *(f16x8*)dst = t0;
        *(f16x8*)(dst + 8) = t1;
    }
}

// ---------------------------------------------------------------------------
// Flash attention fp16 MFMA. Scores arrive pre-scaled into exp2 domain
// (Wq folded with 0.125*log2e). Row sums via mfma(P, ones) — no psum shuffle.
// Masked score -> -1e30 (same semantics as ref's -1e9: p underflows to 0;
// the corr rescale self-heals the degenerate all-masked prefix identically).
// ---------------------------------------------------------------------------
__global__ __launch_bounds__(256)
void flash_mfma(const _Float16* __restrict__ Qg, const _Float16* __restrict__ Kg,
                const _Float16* __restrict__ Vtg, const int* __restrict__ mask,
                _Float16* __restrict__ X)
{
    __shared__ char KsB[8192];                 // [64 keys][128B], swizzled chunks
    __shared__ char VsB[8192];                 // [64 d][128B], swizzled chunks
    __shared__ _Float16 Ps[4][16][72];         // per-wave P tile (144B rows)
    __shared__ int Ms[64];

    const int tid  = threadIdx.x;
    const int lane = tid & 63;
    const int w    = tid >> 6;
    const int g    = lane >> 4;
    const int c    = lane & 15;
    const int cx   = c & 7;
    const int bh   = blockIdx.y;
    const int b    = bh >> 3;
    const int h    = bh & 7;
    const int q0   = blockIdx.x << 6;

    const _Float16* Qb  = Qg  + ((size_t)bh * SLEN + q0 + w * 16) * DH;
    const _Float16* Kb  = Kg  + (size_t)bh * SLEN * DH;
    const _Float16* Vtb = Vtg + (size_t)bh * DH * SLEN;
    const int* mrow = mask + b * SLEN;

    f16x8 qf0 = *(const f16x8*)(Qb + (size_t)c * DH + g * 8);
    f16x8 qf1 = *(const f16x8*)(Qb + (size_t)c * DH + 32 + g * 8);

    f16x8 onesf;
    #pragma unroll
    for (int i = 0; i < 8; ++i) onesf[i] = (_Float16)1.0f;

    const int lane8 = lane >> 3;
    const int schk  = (lane & 7) ^ lane8;
    const int r0    = w * 8 + lane8;
    const _Float16* kSrc0 = Kb  + (size_t)r0 * DH + schk * 8;
    const _Float16* kSrc1 = Kb  + (size_t)(r0 + 32) * DH + schk * 8;
    const _Float16* vSrc0 = Vtb + (size_t)r0 * SLEN + schk * 8;
    const _Float16* vSrc1 = Vtb + (size_t)(r0 + 32) * SLEN + schk * 8;
    char* kDst0 = KsB + w * 1024;
    char* kDst1 = KsB + 4096 + w * 1024;
    char* vDst0 = VsB + w * 1024;
    char* vDst1 = VsB + 4096 + w * 1024;

    float mrun[4] = { -INFINITY, -INFINITY, -INFINITY, -INFINITY };
    f32x4 lacc = (f32x4){0.f, 0.f, 0.f, 0.f};
    f32x4 oacc[4];
    #pragma unroll
    for (int dt = 0; dt < 4; ++dt) oacc[dt] = (f32x4){0.f, 0.f, 0.f, 0.f};

    for (int kt = 0; kt < SLEN / 64; ++kt) {
        const int k0 = kt << 6;
        __syncthreads();
        gload16(kSrc0 + (size_t)k0 * DH, kDst0);
        gload16(kSrc1 + (size_t)k0 * DH, kDst1);
        gload16(vSrc0 + k0, vDst0);
        gload16(vSrc1 + k0, vDst1);
        if (tid < 64) Ms[tid] = mrow[k0 + tid];
        __syncthreads();

        // ---- S = Q K^T (already in exp2 domain)
        f32x4 sacc[4];
        #pragma unroll
        for (int kk = 0; kk < 4; ++kk) sacc[kk] = (f32x4){0.f, 0.f, 0.f, 0.f};
        #pragma unroll
        for (int ks = 0; ks < 2; ++ks) {
            f16x8 qf = ks ? qf1 : qf0;
            #pragma unroll
            for (int kk = 0; kk < 4; ++kk) {
                const int rrow = kk * 16 + c;
                const int off  = rrow * 128 + (((ks * 4 + g) ^ cx) << 4);
                f16x8 kf = *(const f16x8*)(KsB + off);
                sacc[kk] = __builtin_amdgcn_mfma_f32_16x16x32_f16(qf, kf, sacc[kk], 0, 0, 0);
            }
        }

        // ---- mask
        int mk[4];
        #pragma unroll
        for (int kk = 0; kk < 4; ++kk) mk[kk] = Ms[kk * 16 + c];
        #pragma unroll
        for (int kk = 0; kk < 4; ++kk) {
            #pragma unroll
            for (int r = 0; r < 4; ++r)
                sacc[kk][r] = (mk[kk] == 0) ? -1e30f : sacc[kk][r];
        }

        // ---- online softmax (row max across 4 regs x 16 lanes)
        float mx[4], corr[4];
        #pragma unroll
        for (int r = 0; r < 4; ++r)
            mx[r] = fmaxf(fmaxf(sacc[0][r], sacc[1][r]), fmaxf(sacc[2][r], sacc[3][r]));
        #pragma unroll
        for (int off = 1; off < 16; off <<= 1) {
            #pragma unroll
            for (int r = 0; r < 4; ++r) mx[r] = fmaxf(mx[r], __shfl_xor(mx[r], off));
        }
        #pragma unroll
        for (int r = 0; r < 4; ++r) {
            const float mn = fmaxf(mrun[r], mx[r]);
            corr[r] = exp2_hw(mrun[r] - mn);
            mrun[r] = mn;
            #pragma unroll
            for (int kk = 0; kk < 4; ++kk)
                sacc[kk][r] = exp2_hw(sacc[kk][r] - mn);
        }
        #pragma unroll
        for (int r = 0; r < 4; ++r) {
            lacc[r] *= corr[r];
            #pragma unroll
            for (int dt = 0; dt < 4; ++dt) oacc[dt][r] *= corr[r];
        }

        // ---- P -> LDS fp16 (per-wave region; wave-internal ordering)
        #pragma unroll
        for (int kk = 0; kk < 4; ++kk) {
            #pragma unroll
            for (int r = 0; r < 4; ++r)
                Ps[w][g * 4 + r][kk * 16 + c] = (_Float16)sacc[kk][r];
        }

        // ---- O += P V ; l += P·1 (row-sum via matrix pipe)
        #pragma unroll
        for (int ks = 0; ks < 2; ++ks) {
            f16x8 pf = *(const f16x8*)&Ps[w][c][ks * 32 + g * 8];
            lacc = __builtin_amdgcn_mfma_f32_16x16x32_f16(pf, onesf, lacc, 0, 0, 0);
            #pragma unroll
            for (int dt = 0; dt < 4; ++dt) {
                const int rr  = dt * 16 + c;
                const int off = rr * 128 + (((ks * 4 + g) ^ cx) << 4);
                f16x8 vf = *(const f16x8*)(VsB + off);
                oacc[dt] = __builtin_amdgcn_mfma_f32_16x16x32_f16(pf, vf, oacc[dt], 0, 0, 0);
            }
        }
    }

    // ---- epilogue: normalize, store fp16 x[B,S,D]
    const int qg0 = q0 + w * 16;
    #pragma unroll
    for (int r = 0; r < 4; ++r) {
        const float inv = 1.0f / lacc[r];
        const int qrow = qg0 + g * 4 + r;
        _Float16* dst = X + ((size_t)b * SLEN + qrow) * DMODEL + h * DH;
        #pragma unroll
        for (int dt = 0; dt < 4; ++dt)
            dst[dt * 16 + c] = (_Float16)(oacc[dt][r] * inv);
    }
}

// ---------------------------------------------------------------------------
extern "C" void kernel_launch(void* const* d_in, const int* in_sizes, int n_in,
                              void* d_out, int out_size, void* d_ws, size_t ws_size,
                              hipStream_t stream)
{
    const float* query  = (const float*)d_in[0];
    const float* key_in = (const float*)d_in[1];
    const float* value  = (const float*)d_in[2];
    const int*   mask   = (const int*)  d_in[3];
    const float* Wq = (const float*)d_in[4];
    const float* bq = (const float*)d_in[5];
    const float* Wk = (const float*)d_in[6];
    const float* bk = (const float*)d_in[7];
    const float* Wv = (const float*)d_in[8];
    const float* bv = (const float*)d_in[9];
    const float* Wo = (const float*)d_in[10];
    const float* bo = (const float*)d_in[11];
    float* out = (float*)d_out;
    (void)in_sizes; (void)n_in; (void)out_size; (void)ws_size;

    const size_t NE = (size_t)NROWS * DMODEL;      // 4,194,304
    const size_t WN = (size_t)DMODEL * DMODEL;     // 262,144
    _Float16* f   = (_Float16*)d_ws;
    _Float16* qh  = f;
    _Float16* kh  = f + NE;
    _Float16* vth = f + 2 * NE;
    _Float16* xh  = f + 3 * NE;
    _Float16* wqT = f + 4 * NE;
    _Float16* wkT = wqT + WN;
    _Float16* wvT = wkT + WN;
    _Float16* woT = wvT + WN;

    cast_weights<<<dim3(16, 16, 4), 256, 0, stream>>>(Wq, Wk, Wv, Wo, wqT, wkT, wvT, woT);

    dim3 gg(DMODEL / 64, NROWS / 64);   // (8, 128)
    gemm_mfma<1, 1><<<gg, 256, 16384, stream>>>(query,  wqT, bq, QSCALE, qh);
    gemm_mfma<1, 1><<<gg, 256, 16384, stream>>>(key_in, wkT, bk, 1.0f,   kh);
    gemm_mfma<1, 2><<<gg, 256, 28672, stream>>>(value,  wvT, bv, 1.0f,   vth);

    flash_mfma<<<dim3(SLEN / 64, BATCH * NH), 256, 0, stream>>>(qh, kh, vth, mask, xh);

    gemm_mfma<0, 0><<<gg, 256, 16384, stream>>>(xh, woT, bo, 1.0f, out);
}

// Round 5
// 195.644 us; speedup vs baseline: 10.2483x; 1.3336x over previous
//
#include <hip/hip_runtime.h>
#include <math.h>

// Problem constants (B=2, S=4096, D=512, H=8, dh=64)
#define BATCH  2
#define SLEN   4096
#define DMODEL 512
#define NH     8
#define DH     64
#define NROWS  (BATCH * SLEN)   // 8192

// Q-side fold: scores*(1/8)*log2(e) so softmax uses raw v_exp_f32 (2^x)
#define QSCALE 0.18033688011112042f
#define MBIAS  -65504.0f        // fp16-min mask bias; p underflows to 0 after exp2

typedef __attribute__((ext_vector_type(8)))  _Float16 f16x8;
typedef __attribute__((ext_vector_type(4)))  _Float16 f16x4;
typedef __attribute__((ext_vector_type(4)))  float    f32x4;
typedef __attribute__((ext_vector_type(16))) float    f32x16;
typedef __attribute__((ext_vector_type(4)))  unsigned int u32x4;

__device__ __forceinline__ float exp2_hw(float x) {
    float r; asm("v_exp_f32 %0, %1" : "=v"(r) : "v"(x)); return r;   // D = 2^S0
}

// swap: dst lanes[32..63] <-> src lanes[0..31] (lane-aligned l <-> l+32)
__device__ __forceinline__ void pswap(unsigned &a, unsigned &b) {
    asm volatile("v_permlane32_swap_b32 %0, %1" : "+v"(a), "+v"(b));
}

__device__ __forceinline__ unsigned pkrtz(float a, float b) {
    auto p = __builtin_amdgcn_cvt_pkrtz(a, b);   // __fp16 ext_vector(2)
    return __builtin_bit_cast(unsigned, p);
}

__device__ __forceinline__ void gload16(const void* g, void* l) {
    __builtin_amdgcn_global_load_lds(
        (const __attribute__((address_space(1))) unsigned int*)g,
        (__attribute__((address_space(3))) unsigned int*)l, 16, 0, 0);
}

// ---------------------------------------------------------------------------
// Weights: fp32 [K][N] -> fp16 transposed [N][K] (B-fragment reads become rows).
// ---------------------------------------------------------------------------
__global__ __launch_bounds__(256)
void cast_weights(const float* __restrict__ W0, const float* __restrict__ W1,
                  const float* __restrict__ W2, const float* __restrict__ W3,
                  _Float16* __restrict__ T0, _Float16* __restrict__ T1,
                  _Float16* __restrict__ T2, _Float16* __restrict__ T3)
{
    const int z = blockIdx.z;
    const float* W = (z == 0) ? W0 : (z == 1) ? W1 : (z == 2) ? W2 : W3;
    _Float16*    T = (z == 0) ? T0 : (z == 1) ? T1 : (z == 2) ? T2 : T3;
    const float sc = (z == 0) ? QSCALE : 1.0f;

    __shared__ float Ls[32][33];
    const int n0 = blockIdx.x * 32, k0 = blockIdx.y * 32;
    const int row = threadIdx.x >> 3;
    const int c4  = (threadIdx.x & 7) << 2;

    float4 v = *(const float4*)&W[(size_t)(k0 + row) * DMODEL + n0 + c4];
    Ls[row][c4 + 0] = v.x; Ls[row][c4 + 1] = v.y;
    Ls[row][c4 + 2] = v.z; Ls[row][c4 + 3] = v.w;
    __syncthreads();

    f16x4 o;
    #pragma unroll
    for (int j = 0; j < 4; ++j) o[j] = (_Float16)(Ls[c4 + j][row] * sc);
    *(f16x4*)&T[(size_t)(n0 + row) * DMODEL + k0 + c4] = o;
}

// ---------------------------------------------------------------------------
// fp16 MFMA GEMM (unchanged from round 2): C[8192,512] = A @ WT^T + bias.
// ---------------------------------------------------------------------------
template<int AMODE, int OUTMODE>
__global__ __launch_bounds__(256)
void gemm_mfma(const void* __restrict__ Ag, const _Float16* __restrict__ WTg,
               const float* __restrict__ bias, float bscale, void* __restrict__ Cout)
{
    extern __shared__ char smem[];
    char* Asb = smem;            // 8 KB
    char* Bsb = smem + 8192;     // 8 KB
    _Float16* Tr = (_Float16*)(smem + 16384);   // 12 KB, OUTMODE==2 only

    const int tid  = threadIdx.x;
    const int lane = tid & 63;
    const int w    = tid >> 6;
    const int g    = lane >> 4;
    const int c    = lane & 15;
    const int m0   = blockIdx.y * 64;
    const int n0   = blockIdx.x * 64;

    const int lrow = lane >> 3;
    const int schk = (lane & 7) ^ lrow;
    const int brow = w * 8 + lrow;
    const _Float16* bSrc0 = WTg + (size_t)(n0 + brow) * DMODEL + schk * 8;
    const _Float16* bSrc1 = WTg + (size_t)(n0 + brow + 32) * DMODEL + schk * 8;
    char* bDst = Bsb + w * 1024;
    char* aDst = Asb + w * 1024;

    const _Float16* aSrc0 = nullptr; const _Float16* aSrc1 = nullptr;
    const float* aF = nullptr;
    const int arow = tid >> 2;
    const int acp  = (tid & 3) << 1;
    if constexpr (AMODE == 0) {
        const _Float16* Ah = (const _Float16*)Ag;
        aSrc0 = Ah + (size_t)(m0 + brow) * DMODEL + schk * 8;
        aSrc1 = Ah + (size_t)(m0 + brow + 32) * DMODEL + schk * 8;
    } else {
        aF = (const float*)Ag + (size_t)(m0 + arow) * DMODEL;
    }

    f32x4 acc[4];
    #pragma unroll
    for (int nt = 0; nt < 4; ++nt) acc[nt] = (f32x4){0.f, 0.f, 0.f, 0.f};

    for (int k0 = 0; k0 < DMODEL; k0 += 64) {
        float4 a0, a1, a2, a3;
        if constexpr (AMODE == 1) {
            const float* p = aF + k0 + acp * 8;
            a0 = *(const float4*)(p + 0);  a1 = *(const float4*)(p + 4);
            a2 = *(const float4*)(p + 8);  a3 = *(const float4*)(p + 12);
        }
        __syncthreads();
        if constexpr (AMODE == 0) {
            gload16(aSrc0 + k0, aDst);
            gload16(aSrc1 + k0, aDst + 4096);
        } else {
            f16x8 h0, h1;
            h0[0]=(_Float16)a0.x; h0[1]=(_Float16)a0.y; h0[2]=(_Float16)a0.z; h0[3]=(_Float16)a0.w;
            h0[4]=(_Float16)a1.x; h0[5]=(_Float16)a1.y; h0[6]=(_Float16)a1.z; h0[7]=(_Float16)a1.w;
            h1[0]=(_Float16)a2.x; h1[1]=(_Float16)a2.y; h1[2]=(_Float16)a2.z; h1[3]=(_Float16)a2.w;
            h1[4]=(_Float16)a3.x; h1[5]=(_Float16)a3.y; h1[6]=(_Float16)a3.z; h1[7]=(_Float16)a3.w;
            *(f16x8*)(Asb + arow * 128 + (((acp    ) ^ (arow & 7)) << 4)) = h0;
            *(f16x8*)(Asb + arow * 128 + (((acp + 1) ^ (arow & 7)) << 4)) = h1;
        }
        gload16(bSrc0 + k0, bDst);
        gload16(bSrc1 + k0, bDst + 4096);
        __syncthreads();

        #pragma unroll
        for (int ks = 0; ks < 2; ++ks) {
            const int ar = w * 16 + c;
            f16x8 af = *(const f16x8*)(Asb + ar * 128 + ((((ks << 2) + g) ^ (ar & 7)) << 4));
            #pragma unroll
            for (int nt = 0; nt < 4; ++nt) {
                const int br = nt * 16 + c;
                f16x8 bf = *(const f16x8*)(Bsb + br * 128 + ((((ks << 2) + g) ^ (br & 7)) << 4));
                acc[nt] = __builtin_amdgcn_mfma_f32_16x16x32_f16(af, bf, acc[nt], 0, 0, 0);
            }
        }
    }

    const int h = n0 >> 6;
    if constexpr (OUTMODE == 0) {
        float* C = (float*)Cout;
        #pragma unroll
        for (int nt = 0; nt < 4; ++nt) {
            const float bb = bias[n0 + nt * 16 + c];
            #pragma unroll
            for (int r = 0; r < 4; ++r) {
                const int m = m0 + w * 16 + g * 4 + r;
                C[(size_t)m * DMODEL + n0 + nt * 16 + c] = acc[nt][r] + bb;
            }
        }
    } else if constexpr (OUTMODE == 1) {
        _Float16* C = (_Float16*)Cout;
        #pragma unroll
        for (int nt = 0; nt < 4; ++nt) {
            const float bb = bias[n0 + nt * 16 + c] * bscale;
            const int hd = nt * 16 + c;
            #pragma unroll
            for (int r = 0; r < 4; ++r) {
                const int m = m0 + w * 16 + g * 4 + r;
                const int b = m >> 12;
                const int s = m & (SLEN - 1);
                C[(((size_t)b * NH + h) * SLEN + s) * DH + hd] = (_Float16)(acc[nt][r] + bb);
            }
        }
    } else {
        #pragma unroll
        for (int nt = 0; nt < 4; ++nt) {
            const float bb = bias[n0 + nt * 16 + c];
            #pragma unroll
            for (int r = 0; r < 4; ++r)
                Tr[(size_t)(w * 64 + nt * 16 + c) * 24 + g * 4 + r] = (_Float16)(acc[nt][r] + bb);
        }
        const int n = lane;
        f16x8 t0 = *(const f16x8*)&Tr[(size_t)(w * 64 + n) * 24 + 0];
        f16x8 t1 = *(const f16x8*)&Tr[(size_t)(w * 64 + n) * 24 + 8];
        const int b = m0 >> 12;
        const int s = (m0 & (SLEN - 1)) + w * 16;
        _Float16* dst = (_Float16*)Cout + (((size_t)b * NH + h) * DH + n) * SLEN + s;
        *(f16x8*)dst = t0;
        *(f16x8*)(dst + 8) = t1;
    }
}

// ---------------------------------------------------------------------------
// Flash attention, 32x32x16 fp16 MFMA, swapped QK^T, in-register softmax/P.
// Wave = 32 q-rows; block = 4 waves (128 q); KVBLK = 64.
// Layouts (32x32x16): A: lane holds A[row=l&31][k=(l>>5)*8+j]
//                     B: B[k=(l>>5)*8+j][col=l&31]
//                     C/D: D[row=(reg&3)+8*(reg>>2)+4*(l>>5)][col=l&31]
// Mask: seeded into S^T via mfma(mbias_frag, e0_frag, 0) — zero VALU cost.
// P->B-frags: v_cvt_pkrtz pairs + v_permlane32_swap (no P LDS round-trip).
// Row sum l: mfma(ones, P) accumulated in a spare f32x16 (read elem 0).
// ---------------------------------------------------------------------------
__global__ __launch_bounds__(256, 2)
void flash_mfma32(const _Float16* __restrict__ Qg, const _Float16* __restrict__ Kg,
                  const _Float16* __restrict__ Vtg, const int* __restrict__ mask,
                  _Float16* __restrict__ X)
{
    __shared__ char KsB[8192];             // [64 keys][128B], chunk-XOR swizzled
    __shared__ char VsB[8192];             // [64 d][128B]
    __shared__ _Float16 Mb[64];            // per-tile mask bias (0 / -65504)
    __shared__ _Float16 Osc[4][32][72];    // per-wave output transpose scratch

    const int tid  = threadIdx.x;
    const int lane = tid & 63;
    const int w    = tid >> 6;
    const int q    = lane & 31;            // this lane's q column
    const int h    = lane >> 5;            // lane half

    // XCD-aware remap: each XCD owns 2 bh's (K/V fit its 4MB L2)
    const int wg  = blockIdx.x;
    const int ii  = wg >> 3;
    const int bh  = (wg & 7) * 2 + (ii >> 5);
    const int qt  = ii & 31;
    const int b   = bh >> 3;
    const int hh  = bh & 7;
    const int q0  = qt * 128;              // block q base; wave covers +w*32

    const _Float16* Kb  = Kg  + (size_t)bh * SLEN * DH;
    const _Float16* Vtb = Vtg + (size_t)bh * DH * SLEN;
    const int* mrow = mask + (size_t)b * SLEN;

    // Q as B-fragments (4 d-slices), kept in registers
    const _Float16* Qb = Qg + ((size_t)bh * SLEN + q0 + w * 32 + q) * DH;
    f16x8 qf[4];
    #pragma unroll
    for (int ds = 0; ds < 4; ++ds) qf[ds] = *(const f16x8*)(Qb + ds * 16 + h * 8);

    // constant fragments
    f16x8 ef = (f16x8)(_Float16)0;                 // B: 1 at k=0 only
    if (h == 0) ef[0] = (_Float16)1;
    f16x8 onesA;
    #pragma unroll
    for (int i = 0; i < 8; ++i) onesA[i] = (_Float16)1;

    // staging geometry (linear LDS dest, pre-swizzled global source)
    const int l8   = lane >> 3;
    const int schk = (lane & 7) ^ l8;
    const _Float16* kS0 = Kb  + (size_t)(w * 8 + l8) * DH + schk * 8;
    const _Float16* kS1 = kS0 + (size_t)32 * DH;
    const _Float16* vS0 = Vtb + (size_t)(w * 8 + l8) * SLEN + schk * 8;
    const _Float16* vS1 = vS0 + (size_t)32 * SLEN;
    char* kD0 = KsB + w * 1024;  char* kD1 = KsB + 4096 + w * 1024;
    char* vD0 = VsB + w * 1024;  char* vD1 = VsB + 4096 + w * 1024;

    float  mrun = -INFINITY;
    f32x16 lacc = (f32x16)0.f;             // row-sum accumulator (elem 0 used)
    f32x16 oacc[2];
    oacc[0] = (f32x16)0.f; oacc[1] = (f32x16)0.f;

    for (int kt = 0; kt < SLEN / 64; ++kt) {
        const int k0 = kt << 6;
        __syncthreads();                   // all waves done with prev tile
        gload16(kS0 + (size_t)k0 * DH, kD0);
        gload16(kS1 + (size_t)k0 * DH, kD1);
        gload16(vS0 + k0, vD0);
        gload16(vS1 + k0, vD1);
        if (tid < 64) Mb[tid] = mrow[k0 + tid] ? (_Float16)0 : (_Float16)MBIAS;
        __syncthreads();                   // drains vmcnt + lgkmcnt

        // ---- S^T = K Q^T (+ mask bias seed), 2 key-subtiles of 32
        f32x16 st[2];
        #pragma unroll
        for (int kt2 = 0; kt2 < 2; ++kt2) {
            f16x8 mf = (f16x8)(_Float16)0;
            if (h == 0) mf[0] = Mb[q + kt2 * 32];
            st[kt2] = __builtin_amdgcn_mfma_f32_32x32x16_f16(mf, ef, (f32x16)0.f, 0, 0, 0);
            #pragma unroll
            for (int ds = 0; ds < 4; ++ds) {
                const int row = kt2 * 32 + q;
                f16x8 kf = *(const f16x8*)(KsB + row * 128 + ((((ds << 1) + h) ^ (row & 7)) << 4));
                st[kt2] = __builtin_amdgcn_mfma_f32_32x32x16_f16(kf, qf[ds], st[kt2], 0, 0, 0);
            }
        }

        // ---- online softmax: in-lane tree max + one cross-half shuffle
        float a[16];
        #pragma unroll
        for (int e = 0; e < 16; ++e) a[e] = fmaxf(st[0][e], st[1][e]);
        #pragma unroll
        for (int s2 = 8; s2 >= 1; s2 >>= 1) {
            #pragma unroll
            for (int e = 0; e < 8; ++e)
                if (e < s2) a[e] = fmaxf(a[e], a[e + s2]);
        }
        float mx = fmaxf(a[0], __shfl_xor(a[0], 32));
        const float mn   = fmaxf(mrun, mx);
        const float corr = exp2_hw(mrun - mn);
        mrun = mn;

        #pragma unroll
        for (int kt2 = 0; kt2 < 2; ++kt2) {
            #pragma unroll
            for (int e = 0; e < 16; ++e)
                st[kt2][e] = exp2_hw(st[kt2][e] - mn);
        }
        lacc[0] *= corr;
        #pragma unroll
        for (int e = 0; e < 16; ++e) { oacc[0][e] *= corr; oacc[1][e] *= corr; }

        // ---- P -> fp16 B-frags (cvt_pkrtz + permlane32_swap), then PV + l-sum
        #pragma unroll
        for (int ks = 0; ks < 4; ++ks) {
            const int kt2 = ks >> 1, bs = (ks & 1) * 8;
            unsigned W0 = pkrtz(st[kt2][bs + 0], st[kt2][bs + 1]);
            unsigned W1 = pkrtz(st[kt2][bs + 2], st[kt2][bs + 3]);
            unsigned W2 = pkrtz(st[kt2][bs + 4], st[kt2][bs + 5]);
            unsigned W3 = pkrtz(st[kt2][bs + 6], st[kt2][bs + 7]);
            pswap(W0, W2);
            pswap(W1, W3);
            u32x4 pw; pw[0] = W0; pw[1] = W1; pw[2] = W2; pw[3] = W3;
            f16x8 pb = __builtin_bit_cast(f16x8, pw);

            lacc = __builtin_amdgcn_mfma_f32_32x32x16_f16(onesA, pb, lacc, 0, 0, 0);
            #pragma unroll
            for (int dt = 0; dt < 2; ++dt) {
                const int row = dt * 32 + q;
                f16x8 vf = *(const f16x8*)(VsB + row * 128 + ((((ks << 1) + h) ^ (row & 7)) << 4));
                oacc[dt] = __builtin_amdgcn_mfma_f32_32x32x16_f16(vf, pb, oacc[dt], 0, 0, 0);
            }
        }
    }

    // ---- epilogue: normalize O^T, transpose via per-wave LDS, store fp16 X
    const float inv = 1.0f / lacc[0];
    #pragma unroll
    for (int dt = 0; dt < 2; ++dt) {
        #pragma unroll
        for (int r = 0; r < 16; r += 2) {
            const int d = dt * 32 + (r & 3) + 8 * (r >> 2) + 4 * h;   // even
            *(unsigned*)&Osc[w][q][d] = pkrtz(oacc[dt][r] * inv, oacc[dt][r + 1] * inv);
        }
    }
    // wave-internal write->read; compiler orders via lgkmcnt
    const int qr  = lane >> 1;
    const int dh2 = (lane & 1) * 32;
    _Float16* dst = X + ((size_t)b * SLEN + q0 + w * 32 + qr) * DMODEL + hh * DH + dh2;
    #pragma unroll
    for (int p = 0; p < 4; ++p)
        *(f16x8*)(dst + p * 8) = *(const f16x8*)&Osc[w][qr][dh2 + p * 8];
}

// ---------------------------------------------------------------------------
extern "C" void kernel_launch(void* const* d_in, const int* in_sizes, int n_in,
                              void* d_out, int out_size, void* d_ws, size_t ws_size,
                              hipStream_t stream)
{
    const float* query  = (const float*)d_in[0];
    const float* key_in = (const float*)d_in[1];
    const float* value  = (const float*)d_in[2];
    const int*   mask   = (const int*)  d_in[3];
    const float* Wq = (const float*)d_in[4];
    const float* bq = (const float*)d_in[5];
    const float* Wk = (const float*)d_in[6];
    const float* bk = (const float*)d_in[7];
    const float* Wv = (const float*)d_in[8];
    const float* bv = (const float*)d_in[9];
    const float* Wo = (const float*)d_in[10];
    const float* bo = (const float*)d_in[11];
    float* out = (float*)d_out;
    (void)in_sizes; (void)n_in; (void)out_size; (void)ws_size;

    const size_t NE = (size_t)NROWS * DMODEL;      // 4,194,304
    const size_t WN = (size_t)DMODEL * DMODEL;     // 262,144
    _Float16* f   = (_Float16*)d_ws;
    _Float16* qh  = f;
    _Float16* kh  = f + NE;
    _Float16* vth = f + 2 * NE;
    _Float16* xh  = f + 3 * NE;
    _Float16* wqT = f + 4 * NE;
    _Float16* wkT = wqT + WN;
    _Float16* wvT = wkT + WN;
    _Float16* woT = wvT + WN;

    cast_weights<<<dim3(16, 16, 4), 256, 0, stream>>>(Wq, Wk, Wv, Wo, wqT, wkT, wvT, woT);

    dim3 gg(DMODEL / 64, NROWS / 64);   // (8, 128)
    gemm_mfma<1, 1><<<gg, 256, 16384, stream>>>(query,  wqT, bq, QSCALE, qh);
    gemm_mfma<1, 1><<<gg, 256, 16384, stream>>>(key_in, wkT, bk, 1.0f,   kh);
    gemm_mfma<1, 2><<<gg, 256, 28672, stream>>>(value,  wvT, bv, 1.0f,   vth);

    flash_mfma32<<<512, 256, 0, stream>>>(qh, kh, vth, mask, xh);

    gemm_mfma<0, 0><<<gg, 256, 16384, stream>>>(xh, woT, bo, 1.0f, out);
}